// Round 2
// baseline (325.485 us; speedup 1.0000x reference)
//
#include <hip/hip_runtime.h>
#include <stdint.h>

constexpr int N = 65536, K = 512, F = 512;
constexpr float ASCALE = 127.0f / 3.0f;   // activation scale (fixed bound 3.0)

typedef short frag8 __attribute__((ext_vector_type(8)));   // 8 bf16 = 4 VGPRs
typedef float floatx4 __attribute__((ext_vector_type(4))); // MFMA C/D

// round-half-even then clip to [-127,127]; result integer-valued fp32
__device__ __forceinline__ float qclamp(float v, float s) {
    float q = rintf(v * s);
    return fminf(fmaxf(q, -127.0f), 127.0f);
}
// pack two fp32 (integer-valued, exact in bf16) into 2 bf16 via truncation
__device__ __forceinline__ unsigned int packbf(float a, float b) {
    union { float f; unsigned u; } ua, ub; ua.f = a; ub.f = b;
    return (ua.u >> 16) | (ub.u & 0xffff0000u);
}

// --- phase 1: per-column abs-max (coalesced) via bit-atomicMax ---
// 8 blocks x 512 threads; thread owns column t, scans 64 rows coalesced.
__global__ void wmax_kernel(const float* __restrict__ kern,
                            unsigned int* __restrict__ wmax) {
    int col = threadIdx.x;
    int r0 = blockIdx.x * 64;
    float m = 0.f;
    #pragma unroll 8
    for (int r = 0; r < 64; ++r)
        m = fmaxf(m, fabsf(kern[(size_t)(r0 + r) * F + col]));
    union { float f; unsigned u; } c; c.f = m;   // positive floats order as uints
    atomicMax(wmax + col, c.u);
}

// --- phase 2: quantize + transpose -> wT[f][k] bf16; dscale[f] ---
// 64 blocks (kb 0..7, fb 0..7) x 256 threads; 64x64 tile through LDS.
__global__ void quantw_kernel(const float* __restrict__ kern,
                              const unsigned int* __restrict__ wmax,
                              unsigned short* __restrict__ wT,
                              float* __restrict__ dscale) {
    __shared__ float tile[64][65];
    int kb = blockIdx.x >> 3, fb = blockIdx.x & 7;
    int t = threadIdx.x;
    int c = t & 63, r4 = t >> 2 >> 4;  // r4 = t>>6
    r4 = t >> 6;
    #pragma unroll
    for (int p = 0; p < 16; ++p) {
        int r = p * 4 + r4;
        tile[r][c] = kern[(size_t)(kb * 64 + r) * F + fb * 64 + c];
    }
    __syncthreads();
    #pragma unroll
    for (int p = 0; p < 16; ++p) {
        int fr = p * 4 + r4;
        union { float f; unsigned u; } mb; mb.u = wmax[fb * 64 + fr];
        float wsc = 127.0f / fmaxf(mb.f, 1e-7f);
        float q = qclamp(tile[c][fr], wsc);
        union { float f; unsigned u; } qu; qu.f = q;
        wT[(size_t)(fb * 64 + fr) * K + kb * 64 + c] = (unsigned short)(qu.u >> 16);
    }
    if (kb == 0 && t < 64) {
        int f = fb * 64 + t;
        union { float f; unsigned u; } mb; mb.u = wmax[f];
        dscale[f] = 3.0f * fmaxf(mb.f, 1e-7f) / 16129.0f;  // 1/(a_scale*w_scale)
    }
}

// --- phase 3: fused quant-x + int-exact bf16 MFMA GEMM (m97-style) ---
// 128x128 tile, BK=64, 256 threads (4 waves, each a 64x64 quadrant).
// A: x fp32 -> regs (prefetched next-iter) -> quantize -> LDS (xor-swizzled).
// B: wT bf16 -> LDS via global_load_lds width=16 (xor-swizzled source pick).
__global__ __launch_bounds__(256, 3)
void gemm_kernel(const float* __restrict__ x,
                 const unsigned short* __restrict__ wT,
                 const float* __restrict__ dscale,
                 const float* __restrict__ bias,
                 float* __restrict__ out) {
    __shared__ unsigned short As[128 * 64];   // [row][chunk^row&7], rows of 128B
    __shared__ unsigned short Bs[128 * 64];

    int t = threadIdx.x;
    int lane = t & 63, wave = t >> 6;
    int bm = blockIdx.x >> 2, bn = blockIdx.x & 3;
    int m16 = lane & 15, quad = lane >> 4;

    floatx4 acc[4][4];
    #pragma unroll
    for (int i = 0; i < 4; ++i)
        #pragma unroll
        for (int j = 0; j < 4; ++j) acc[i][j] = (floatx4){0.f, 0.f, 0.f, 0.f};

    // A staging: thread -> row ar = t>>1, half ah = t&1 (32 floats = 8 float4)
    int ar = t >> 1, ah = t & 1;
    const float* xp = x + (size_t)(bm * 128 + ar) * K + ah * 32;
    unsigned short* asw = &As[ar * 64];
    int arsw = ar & 7;

    // B staging: lane -> row (lane>>3), source chunk (lane&7)^(lane>>3)
    int brow = lane >> 3;
    int bchunk = (lane & 7) ^ brow;
    const unsigned short* wbase =
        wT + (size_t)(bn * 128 + wave * 32 + brow) * K + bchunk * 8;

    float4 xr[8];
    #pragma unroll
    for (int j = 0; j < 8; ++j) xr[j] = *(const float4*)(xp + j * 4);

    for (int kt = 0; kt < 8; ++kt) {
        // quantize current x regs -> As (swizzled 16B chunks)
        #pragma unroll
        for (int j = 0; j < 4; ++j) {
            float4 a = xr[2 * j], b = xr[2 * j + 1];
            uint4 w;
            w.x = packbf(qclamp(a.x, ASCALE), qclamp(a.y, ASCALE));
            w.y = packbf(qclamp(a.z, ASCALE), qclamp(a.w, ASCALE));
            w.z = packbf(qclamp(b.x, ASCALE), qclamp(b.y, ASCALE));
            w.w = packbf(qclamp(b.z, ASCALE), qclamp(b.w, ASCALE));
            int c = (ah * 4 + j) ^ arsw;
            *(uint4*)&asw[c * 8] = w;
        }
        // B tile -> LDS, async 16B, lane-contiguous dest (no pad; xor on source)
        #pragma unroll
        for (int i = 0; i < 4; ++i) {
            const unsigned short* g = wbase + (size_t)(i * 8) * K + kt * 64;
            auto* lp = (__attribute__((address_space(3))) unsigned int*)
                           &Bs[(wave * 32 + i * 8) * 64];
            __builtin_amdgcn_global_load_lds(
                (const __attribute__((address_space(1))) unsigned int*)g, lp, 16, 0, 0);
        }
        __syncthreads();

        // prefetch next x chunk into regs (latency hides under MFMA below)
        if (kt < 7) {
            #pragma unroll
            for (int j = 0; j < 8; ++j)
                xr[j] = *(const float4*)(xp + (kt + 1) * 64 + j * 4);
        }

        const unsigned short* arow = &As[((wave >> 1) * 64 + m16) * 64];
        const unsigned short* brw  = &Bs[((wave & 1) * 64 + m16) * 64];
        int sw = m16 & 7;
        #pragma unroll
        for (int s = 0; s < 2; ++s) {
            int pc = (4 * s + quad) ^ sw;
            frag8 af[4], bf[4];
            #pragma unroll
            for (int mt = 0; mt < 4; ++mt)
                af[mt] = *(const frag8*)&arow[mt * 16 * 64 + pc * 8];
            #pragma unroll
            for (int nt = 0; nt < 4; ++nt)
                bf[nt] = *(const frag8*)&brw[nt * 16 * 64 + pc * 8];
            #pragma unroll
            for (int mt = 0; mt < 4; ++mt)
                #pragma unroll
                for (int nt = 0; nt < 4; ++nt)
                    acc[mt][nt] = __builtin_amdgcn_mfma_f32_16x16x32_bf16(
                        af[mt], bf[nt], acc[mt][nt], 0, 0, 0);
        }
        __syncthreads();
    }

    // epilogue: C layout col=lane&15, row=quad*4+reg (m89/m91-verified)
    #pragma unroll
    for (int nt = 0; nt < 4; ++nt) {
        int col = bn * 128 + (wave & 1) * 64 + nt * 16 + m16;
        float ds = dscale[col], bv = bias[col];
        #pragma unroll
        for (int mt = 0; mt < 4; ++mt) {
            size_t row = bm * 128 + (wave >> 1) * 64 + mt * 16 + quad * 4;
            #pragma unroll
            for (int r = 0; r < 4; ++r)
                out[(row + r) * F + col] = acc[mt][nt][r] * ds + bv;
        }
    }
}

extern "C" void kernel_launch(void* const* d_in, const int* in_sizes, int n_in,
                              void* d_out, int out_size, void* d_ws, size_t ws_size,
                              hipStream_t stream) {
    const float* x    = (const float*)d_in[0];
    const float* kern = (const float*)d_in[1];
    const float* bias = (const float*)d_in[2];
    float* out = (float*)d_out;

    unsigned short* wT = (unsigned short*)d_ws;                 // 512 KB
    float* dscale = (float*)((char*)d_ws + (size_t)K * F * 2);  // 2 KB
    unsigned int* wmax = (unsigned int*)((char*)d_ws + (size_t)K * F * 2 + 2048);

    hipMemsetAsync(wmax, 0, F * sizeof(unsigned int), stream);
    wmax_kernel<<<8, 512, 0, stream>>>(kern, wmax);
    quantw_kernel<<<64, 256, 0, stream>>>(kern, wmax, wT, dscale);
    gemm_kernel<<<(N / 128) * (F / 128), 256, 0, stream>>>(x, wT, dscale, bias, out);
}

// Round 3
// 318.432 us; speedup vs baseline: 1.0222x; 1.0222x over previous
//
#include <hip/hip_runtime.h>
#include <stdint.h>

constexpr int N = 65536, K = 512, F = 512;
constexpr float ASCALE = 127.0f / 3.0f;   // activation scale (fixed bound 3.0)

typedef short frag8 __attribute__((ext_vector_type(8)));   // 8 bf16 = 4 VGPRs
typedef float floatx4 __attribute__((ext_vector_type(4))); // MFMA C/D

// round-half-even then clip to [-127,127]; result integer-valued fp32
__device__ __forceinline__ float qclamp(float v, float s) {
    float q = rintf(v * s);
    return fminf(fmaxf(q, -127.0f), 127.0f);
}
// pack two fp32 (integer-valued, exact in bf16) into 2 bf16 via truncation
__device__ __forceinline__ unsigned int packbf(float a, float b) {
    union { float f; unsigned u; } ua, ub; ua.f = a; ub.f = b;
    return (ua.u >> 16) | (ub.u & 0xffff0000u);
}

// --- phase 1: per-column abs-max (coalesced) via bit-atomicMax ---
__global__ void wmax_kernel(const float* __restrict__ kern,
                            unsigned int* __restrict__ wmax) {
    int col = threadIdx.x;
    int r0 = blockIdx.x * 64;
    float m = 0.f;
    #pragma unroll 8
    for (int r = 0; r < 64; ++r)
        m = fmaxf(m, fabsf(kern[(size_t)(r0 + r) * F + col]));
    union { float f; unsigned u; } c; c.f = m;   // positive floats order as uints
    atomicMax(wmax + col, c.u);
}

// --- phase 2: quantize + transpose -> wT[f][k] bf16; dscale[f] ---
__global__ void quantw_kernel(const float* __restrict__ kern,
                              const unsigned int* __restrict__ wmax,
                              unsigned short* __restrict__ wT,
                              float* __restrict__ dscale) {
    __shared__ float tile[64][65];
    int kb = blockIdx.x >> 3, fb = blockIdx.x & 7;
    int t = threadIdx.x;
    int c = t & 63, r4 = t >> 6;
    #pragma unroll
    for (int p = 0; p < 16; ++p) {
        int r = p * 4 + r4;
        tile[r][c] = kern[(size_t)(kb * 64 + r) * F + fb * 64 + c];
    }
    __syncthreads();
    #pragma unroll
    for (int p = 0; p < 16; ++p) {
        int fr = p * 4 + r4;
        union { float f; unsigned u; } mb; mb.u = wmax[fb * 64 + fr];
        float wsc = 127.0f / fmaxf(mb.f, 1e-7f);
        float q = qclamp(tile[c][fr], wsc);
        union { float f; unsigned u; } qu; qu.f = q;
        wT[(size_t)(fb * 64 + fr) * K + kb * 64 + c] = (unsigned short)(qu.u >> 16);
    }
    if (kb == 0 && t < 64) {
        int f = fb * 64 + t;
        union { float f; unsigned u; } mb; mb.u = wmax[f];
        dscale[f] = 3.0f * fmaxf(mb.f, 1e-7f) / 16129.0f;  // 1/(a_scale*w_scale)
    }
}

// --- phase 3: BN=512 single-pass-over-x GEMM ---
// 1024 blocks x 512 threads (8 waves). Block out-tile: 64 rows x all 512 cols.
// Wave w: 64x64 tile at col w*64 (4x4 MFMA 16x16x32 bf16, int-exact).
// A (x): fp32 regs -> quantize -> LDS double-buffer (xor-swizzled), 1 barrier/iter.
// B (wT): L2-resident (512 KB/XCD); lanes load frags DIRECTLY from global.
__global__ __launch_bounds__(512, 4)
void gemm_kernel(const float* __restrict__ x,
                 const unsigned short* __restrict__ wT,
                 const float* __restrict__ dscale,
                 const float* __restrict__ bias,
                 float* __restrict__ out) {
    __shared__ unsigned short As[2][64 * 64];   // [buf][row][chunk^row&7]

    int t = threadIdx.x;
    int lane = t & 63, wave = t >> 6;
    int bm = blockIdx.x;
    int m16 = lane & 15, quad = lane >> 4;

    floatx4 acc[4][4];
    #pragma unroll
    for (int i = 0; i < 4; ++i)
        #pragma unroll
        for (int j = 0; j < 4; ++j) acc[i][j] = (floatx4){0.f, 0.f, 0.f, 0.f};

    // A staging map: thread -> row t>>3, 16B chunk t&7 (32B = 2 float4 per iter)
    int arow = t >> 3, ac = t & 7;
    int aphys = ac ^ (arow & 7);                 // xor swizzle: 2-way banks (free)
    const float* xp = x + (size_t)(bm * 64 + arow) * K + ac * 8;
    unsigned short* asl[2] = {&As[0][arow * 64 + aphys * 8],
                              &As[1][arow * 64 + aphys * 8]};

    // B frag base: lane (m16,quad) of wave -> row n0+nt*16+m16, chunk s*4+quad
    const unsigned short* wb = wT + (size_t)(wave * 64 + m16) * K + quad * 8;

    // prologue: stage kt=0, prefetch kt=1
    float4 xa = *(const float4*)(xp);
    float4 xb = *(const float4*)(xp + 4);
    {
        uint4 w;
        w.x = packbf(qclamp(xa.x, ASCALE), qclamp(xa.y, ASCALE));
        w.y = packbf(qclamp(xa.z, ASCALE), qclamp(xa.w, ASCALE));
        w.z = packbf(qclamp(xb.x, ASCALE), qclamp(xb.y, ASCALE));
        w.w = packbf(qclamp(xb.z, ASCALE), qclamp(xb.w, ASCALE));
        *(uint4*)asl[0] = w;
    }
    xa = *(const float4*)(xp + 64);
    xb = *(const float4*)(xp + 68);
    __syncthreads();

    int asw = (m16 & 7);
    for (int kt = 0; kt < 8; ++kt) {
        int buf = kt & 1;
        const unsigned short* wk = wb + kt * 64;

        // B s=0 frags: direct global (L2-hit), issued first to hide latency
        frag8 bf0[4], bf1[4];
        #pragma unroll
        for (int nt = 0; nt < 4; ++nt)
            bf0[nt] = *(const frag8*)(wk + (size_t)(nt * 16) * K);

        // quantize prefetched regs (kt+1) -> other LDS buffer
        if (kt < 7) {
            uint4 w;
            w.x = packbf(qclamp(xa.x, ASCALE), qclamp(xa.y, ASCALE));
            w.y = packbf(qclamp(xa.z, ASCALE), qclamp(xa.w, ASCALE));
            w.z = packbf(qclamp(xb.x, ASCALE), qclamp(xb.y, ASCALE));
            w.w = packbf(qclamp(xb.z, ASCALE), qclamp(xb.w, ASCALE));
            *(uint4*)asl[buf ^ 1] = w;
        }
        // prefetch x for kt+2
        if (kt < 6) {
            xa = *(const float4*)(xp + (kt + 2) * 64);
            xb = *(const float4*)(xp + (kt + 2) * 64 + 4);
        }

        // B s=1 frags in flight while s=0 MFMAs run
        #pragma unroll
        for (int nt = 0; nt < 4; ++nt)
            bf1[nt] = *(const frag8*)(wk + (size_t)(nt * 16) * K + 4 * 8);

        const unsigned short* ab = &As[buf][m16 * 64];
        // s = 0
        {
            int pc = quad ^ asw;
            frag8 af[4];
            #pragma unroll
            for (int mt = 0; mt < 4; ++mt)
                af[mt] = *(const frag8*)&ab[mt * 16 * 64 + pc * 8];
            #pragma unroll
            for (int mt = 0; mt < 4; ++mt)
                #pragma unroll
                for (int nt = 0; nt < 4; ++nt)
                    acc[mt][nt] = __builtin_amdgcn_mfma_f32_16x16x32_bf16(
                        af[mt], bf0[nt], acc[mt][nt], 0, 0, 0);
        }
        // s = 1
        {
            int pc = (4 + quad) ^ asw;
            frag8 af[4];
            #pragma unroll
            for (int mt = 0; mt < 4; ++mt)
                af[mt] = *(const frag8*)&ab[mt * 16 * 64 + pc * 8];
            #pragma unroll
            for (int mt = 0; mt < 4; ++mt)
                #pragma unroll
                for (int nt = 0; nt < 4; ++nt)
                    acc[mt][nt] = __builtin_amdgcn_mfma_f32_16x16x32_bf16(
                        af[mt], bf1[nt], acc[mt][nt], 0, 0, 0);
        }
        __syncthreads();
    }

    // epilogue: C layout col=lane&15, row=quad*4+reg (m89/m91-verified)
    #pragma unroll
    for (int nt = 0; nt < 4; ++nt) {
        int col = wave * 64 + nt * 16 + m16;
        float ds = dscale[col], bv = bias[col];
        #pragma unroll
        for (int mt = 0; mt < 4; ++mt) {
            size_t row = (size_t)bm * 64 + mt * 16 + quad * 4;
            #pragma unroll
            for (int r = 0; r < 4; ++r)
                out[(row + r) * F + col] = acc[mt][nt][r] * ds + bv;
        }
    }
}

extern "C" void kernel_launch(void* const* d_in, const int* in_sizes, int n_in,
                              void* d_out, int out_size, void* d_ws, size_t ws_size,
                              hipStream_t stream) {
    const float* x    = (const float*)d_in[0];
    const float* kern = (const float*)d_in[1];
    const float* bias = (const float*)d_in[2];
    float* out = (float*)d_out;

    unsigned short* wT = (unsigned short*)d_ws;                 // 512 KB
    float* dscale = (float*)((char*)d_ws + (size_t)K * F * 2);  // 2 KB
    unsigned int* wmax = (unsigned int*)((char*)d_ws + (size_t)K * F * 2 + 2048);

    hipMemsetAsync(wmax, 0, F * sizeof(unsigned int), stream);
    wmax_kernel<<<8, 512, 0, stream>>>(kern, wmax);
    quantw_kernel<<<64, 256, 0, stream>>>(kern, wmax, wT, dscale);
    gemm_kernel<<<N / 64, 512, 0, stream>>>(x, wT, dscale, bias, out);
}